// Round 3
// baseline (365.821 us; speedup 1.0000x reference)
//
#include <hip/hip_runtime.h>

// sbvr decode: decoded[g,l] = sum_s coeff_cache[coeff_idx[g], s] * ((bvr[g,s]>>l)&1)
// G = 4,194,304 groups, S = 4 sums, L = 16 elements/group, out = 64M fp32 (256 MB).
//
// v4: TWO-PASS split. Evidence so far: decode kernel stuck at ~140-165 us
// (dur_us - 165us poison fill - small restores; fill dispatch IDs are all
// == 5 mod 6 -> 6-dispatch iteration) vs a 53 us compulsory floor, and
// INSENSITIVE to MLP (v2), store path (v3), grid shape. The two surviving
// models both blame the random 16 B coeff_cache gather inside the streaming
// kernel: (a) the 1 GiB poison fill flushes L2 every iteration and 1.3 GB of
// streamed traffic thrashes it, so gathers miss to HBM fetching a 64-128 B
// line per 16 B row -> +268-537 MB hidden traffic (3x inflation, kernel IS
// BW-bound -> explains all the neutral results); (b) 4.2 M random L2
// transactions throttle the read pipeline that pure-stream copies never see.
//
// Fix for both: quarantine the randomness.
//   Pass 1: ws[g] = coeff_cache[coeff_idx[g]]   (16 MB idx + gather + 64 MB
//           dense write; only 80 MB of stream pressure around the gather)
//   Pass 2: pure aligned streams: ws (64 MB, L3-warm) + bvr (64 MB) -> out
//           (256 MB). This is exactly the regime where copy kernels hit
//           6.3 TB/s.
// Falls back to the single-pass kernel if ws_size < 64 MB.
//
// NOTE: __builtin_nontemporal_* requires native ext_vector_type, not the
// HIP_vector_type structs (int4/float4) — hence i32x4/f32x4 below.

#define NUM_SUMS 4
#define BVR_LEN 16

typedef int   i32x4 __attribute__((ext_vector_type(4)));
typedef float f32x4 __attribute__((ext_vector_type(4)));

static constexpr int NUM_GROUPS   = (8192 * 8192) / 16;   // 4,194,304
static constexpr int TOTAL_ITEMS  = NUM_GROUPS * 4;       // 16,777,216 quarter-groups
static constexpr int BLOCK        = 256;
static constexpr size_t WS_NEEDED = (size_t)NUM_GROUPS * 16;  // 64 MB of f32x4

// ---------------- Pass 1: gather coeffs into dense ws ----------------
__global__ __launch_bounds__(BLOCK) void sbvr_gather_kernel(
        const float* __restrict__ coeff_cache,   // [65536, 4]
        const int*   __restrict__ coeff_idx,     // [G]
        f32x4*       __restrict__ cws)           // [G]
{
    const int g = blockIdx.x * BLOCK + threadIdx.x;
    // idx stream: nontemporal (read once). Gather: normal cached (1 MB table).
    const int idx = __builtin_nontemporal_load(coeff_idx + g);
    // Cached store: ws re-read immediately by pass 2 -> keep in L2/L3.
    cws[g] = ((const f32x4*)coeff_cache)[idx];
}

// ---------------- Pass 2: pure-stream decode ----------------
__global__ __launch_bounds__(BLOCK) void sbvr_decode_kernel(
        const f32x4* __restrict__ cws,           // [G] gathered coeffs
        const int*   __restrict__ bvr,           // [G, 4]
        float*       __restrict__ out)           // [G * 16]
{
    const int t  = blockIdx.x * BLOCK + threadIdx.x;
    const int g  = t >> 2;
    const int q4 = (t & 3) * 4;

    const i32x4 b = __builtin_nontemporal_load((const i32x4*)bvr + g);
    const f32x4 c = cws[g];                       // dense, L3-warm from pass 1

    f32x4 r;
#pragma unroll
    for (int j = 0; j < 4; ++j) {
        const int l = q4 + j;
        // accumulate in the reference's s-order (s = 0..3) in fp32
        float acc = ((b.x >> l) & 1) ? c.x : 0.0f;
        acc      += ((b.y >> l) & 1) ? c.y : 0.0f;
        acc      += ((b.z >> l) & 1) ? c.z : 0.0f;
        acc      += ((b.w >> l) & 1) ? c.w : 0.0f;
        r[j] = acc;
    }
    __builtin_nontemporal_store(r, (f32x4*)out + t);
}

// ---------------- Fallback: single-pass (v1 structure) ----------------
__global__ __launch_bounds__(BLOCK) void sbvr_fused_kernel(
        const float* __restrict__ coeff_cache,
        const int*   __restrict__ coeff_idx,
        const int*   __restrict__ bvr,
        float*       __restrict__ out)
{
    const int t  = blockIdx.x * BLOCK + threadIdx.x;
    const int g  = t >> 2;
    const int q4 = (t & 3) * 4;

    const int   idx = __builtin_nontemporal_load(coeff_idx + g);
    const i32x4 b   = __builtin_nontemporal_load((const i32x4*)bvr + g);
    const f32x4 c   = ((const f32x4*)coeff_cache)[idx];

    f32x4 r;
#pragma unroll
    for (int j = 0; j < 4; ++j) {
        const int l = q4 + j;
        float acc = ((b.x >> l) & 1) ? c.x : 0.0f;
        acc      += ((b.y >> l) & 1) ? c.y : 0.0f;
        acc      += ((b.z >> l) & 1) ? c.z : 0.0f;
        acc      += ((b.w >> l) & 1) ? c.w : 0.0f;
        r[j] = acc;
    }
    __builtin_nontemporal_store(r, (f32x4*)out + t);
}

extern "C" void kernel_launch(void* const* d_in, const int* in_sizes, int n_in,
                              void* d_out, int out_size, void* d_ws, size_t ws_size,
                              hipStream_t stream) {
    const float* coeff_cache = (const float*)d_in[0];
    const int*   coeff_idx   = (const int*)d_in[1];
    const int*   bvr         = (const int*)d_in[2];
    float*       out         = (float*)d_out;

    if (d_ws != nullptr && ws_size >= WS_NEEDED) {
        f32x4* cws = (f32x4*)d_ws;
        sbvr_gather_kernel<<<NUM_GROUPS / BLOCK, BLOCK, 0, stream>>>(
                coeff_cache, coeff_idx, cws);
        sbvr_decode_kernel<<<TOTAL_ITEMS / BLOCK, BLOCK, 0, stream>>>(
                cws, bvr, out);
    } else {
        sbvr_fused_kernel<<<TOTAL_ITEMS / BLOCK, BLOCK, 0, stream>>>(
                coeff_cache, coeff_idx, bvr, out);
    }
}